// Round 2
// baseline (264.926 us; speedup 1.0000x reference)
//
#include <hip/hip_runtime.h>
#include <math.h>

typedef unsigned int uint32;
typedef __attribute__((ext_vector_type(4))) unsigned int uint4v;

// out[r][c] = h[r][c] * S[c][c], S diagonal +-1 (fp32). Multiply by +-1.0f is
// exactly an XOR of the fp32 sign bit with S[c][c]'s sign bit.
__global__ __launch_bounds__(256) void ParityOperator_62981400428726_kernel(
    const uint32* __restrict__ h,     // fp32 bits
    const uint32* __restrict__ S,     // fp32 bits, dim x dim dense diagonal
    uint32* __restrict__ out,         // fp32 bits
    int dim,                           // 4096
    long long n_chunks)                // total elements / 4
{
    const int chunks_per_row = dim >> 2;  // 1024 for dim=4096
    const long long tid    = (long long)blockIdx.x * blockDim.x + threadIdx.x;
    const long long stride = (long long)gridDim.x * blockDim.x;

    const uint4v* __restrict__ hv = (const uint4v*)h;
    uint4v* __restrict__ ov = (uint4v*)out;

    if ((stride % chunks_per_row) == 0) {
        // Fast path: each thread's column-chunk is loop-invariant -> load the
        // 4 sign masks from S's diagonal exactly once.
        const int c0 = (int)(tid % chunks_per_row) * 4;
        uint32 mask[4];
#pragma unroll
        for (int j = 0; j < 4; ++j) {
            const long long c = c0 + j;
            mask[j] = S[c * (long long)dim + c] & 0x80000000u;
        }
        for (long long i = tid; i < n_chunks; i += stride) {
            uint4v v = hv[i];
#pragma unroll
            for (int j = 0; j < 4; ++j) v[j] ^= mask[j];
            ov[i] = v;
        }
    } else {
        // General fallback: recompute masks per iteration (cached diag lines).
        for (long long i = tid; i < n_chunks; i += stride) {
            const int c0 = (int)(i % chunks_per_row) * 4;
            uint4v v = hv[i];
#pragma unroll
            for (int j = 0; j < 4; ++j) {
                const long long c = c0 + j;
                v[j] ^= (S[c * (long long)dim + c] & 0x80000000u);
            }
            ov[i] = v;
        }
    }
}

extern "C" void kernel_launch(void* const* d_in, const int* in_sizes, int n_in,
                              void* d_out, int out_size, void* d_ws, size_t ws_size,
                              hipStream_t stream) {
    (void)n_in; (void)d_ws; (void)ws_size; (void)out_size;
    const uint32* h = (const uint32*)d_in[0];
    const uint32* S = (const uint32*)d_in[1];
    uint32* out = (uint32*)d_out;

    // dim = sqrt(|S|)
    const long long s_elems = (long long)in_sizes[1];
    int dim = (int)llroundl(sqrtl((long double)s_elems));
    const long long n = (long long)in_sizes[0];
    const long long n_chunks = n >> 2;  // 4 fp32 per 16B chunk

    const int block = 256;
    // 2048 blocks * 256 threads = 524288 = 512 * 1024 -> stride is a multiple
    // of chunks_per_row (1024) for dim=4096, enabling the fast path.
    // 2048 blocks / 256 CUs = 8 blocks/CU; 16 iterations/thread.
    int grid = 2048;
    if ((long long)grid * block > n_chunks) {
        grid = (int)((n_chunks + block - 1) / block);
        if (grid < 1) grid = 1;
    }

    ParityOperator_62981400428726_kernel<<<grid, block, 0, stream>>>(
        h, S, out, dim, n_chunks);
}

// Round 3
// 262.704 us; speedup vs baseline: 1.0085x; 1.0085x over previous
//
#include <hip/hip_runtime.h>
#include <math.h>

typedef unsigned int u32;
typedef __attribute__((ext_vector_type(4))) unsigned int uint4v;

// ---------------------------------------------------------------------------
// out[r][c] = h[r][c] * S[c][c], S diagonal +-1 (fp32). Multiply by +-1.0f is
// exactly an XOR of the fp32 sign bit with sign(S[c][c]).
// Two-kernel plan: (1) compact S's diagonal sign bits into a 16 KB array in
// d_ws (kills the scattered 16-KB-stride S reads in the hot kernel);
// (2) flat streamer, 4x16B chunks per thread, loads batched before stores for
// MLP=5, non-temporal stores (out is never re-read).
// ---------------------------------------------------------------------------

__global__ __launch_bounds__(256) void parity_mask_kernel(
    const u32* __restrict__ S, u32* __restrict__ mask, int dim)
{
    const int c = blockIdx.x * blockDim.x + threadIdx.x;
    if (c < dim) mask[c] = S[(long long)c * dim + c] & 0x80000000u;
}

__global__ __launch_bounds__(256) void parity_apply_kernel(
    const uint4v* __restrict__ hv,
    const uint4v* __restrict__ maskv,   // dim/4 entries (sign masks, 16B each)
    uint4v* __restrict__ ov,
    int cpr,                            // chunks per row = dim/4
    long long n_chunks)
{
    const long long tid = (long long)blockIdx.x * blockDim.x + threadIdx.x;
    const long long s   = (long long)gridDim.x * blockDim.x;

    // Grid is sized so 4*s >= n_chunks: chunk j belongs to thread (j % s) at
    // unrolled slot (j / s) in [0,4). Fast path covers full-4 threads when the
    // stride preserves the column chunk (s % cpr == 0 -> one mask reused).
    if ((s % cpr) == 0 && tid + 3 * s < n_chunks) {
        const uint4v m = maskv[(int)(tid % cpr)];
        uint4v v0 = hv[tid];
        uint4v v1 = hv[tid +     s];
        uint4v v2 = hv[tid + 2 * s];
        uint4v v3 = hv[tid + 3 * s];
        v0 ^= m; v1 ^= m; v2 ^= m; v3 ^= m;
        __builtin_nontemporal_store(v0, &ov[tid]);
        __builtin_nontemporal_store(v1, &ov[tid +     s]);
        __builtin_nontemporal_store(v2, &ov[tid + 2 * s]);
        __builtin_nontemporal_store(v3, &ov[tid + 3 * s]);
    } else {
        for (long long i = tid; i < n_chunks; i += s) {
            uint4v m = maskv[(int)(i % cpr)];
            uint4v v = hv[i];
            v ^= m;
            __builtin_nontemporal_store(v, &ov[i]);
        }
    }
}

// Fallback (ws too small): round-2 kernel reading S directly.
__global__ __launch_bounds__(256) void parity_fallback_kernel(
    const u32* __restrict__ h, const u32* __restrict__ S, u32* __restrict__ out,
    int dim, long long n_chunks)
{
    const int cpr = dim >> 2;
    const long long tid    = (long long)blockIdx.x * blockDim.x + threadIdx.x;
    const long long stride = (long long)gridDim.x * blockDim.x;
    const uint4v* hv = (const uint4v*)h;
    uint4v* ov = (uint4v*)out;
    for (long long i = tid; i < n_chunks; i += stride) {
        const int c0 = (int)(i % cpr) * 4;
        uint4v v = hv[i];
#pragma unroll
        for (int j = 0; j < 4; ++j) {
            const long long c = c0 + j;
            v[j] ^= (S[c * (long long)dim + c] & 0x80000000u);
        }
        ov[i] = v;
    }
}

extern "C" void kernel_launch(void* const* d_in, const int* in_sizes, int n_in,
                              void* d_out, int out_size, void* d_ws, size_t ws_size,
                              hipStream_t stream) {
    (void)n_in; (void)out_size;
    const u32* h = (const u32*)d_in[0];
    const u32* S = (const u32*)d_in[1];
    u32* out = (u32*)d_out;

    const long long s_elems = (long long)in_sizes[1];
    const int dim = (int)llroundl(sqrtl((long double)s_elems));  // 4096
    const long long n = (long long)in_sizes[0];
    const long long n_chunks = n >> 2;        // 4 fp32 per 16B chunk
    const int cpr = dim >> 2;                 // 1024

    const int block = 256;
    if (ws_size >= (size_t)dim * sizeof(u32) && (dim & 3) == 0) {
        u32* mask = (u32*)d_ws;
        parity_mask_kernel<<<(dim + block - 1) / block, block, 0, stream>>>(
            S, mask, dim);
        // 4 chunks/thread, no loop: grid = ceil(n_chunks / (block*4)).
        // For 8192x4096: 8192 blocks; stride = 2,097,152 = 2048*1024 -> fast
        // path (stride % cpr == 0) holds.
        long long grid = (n_chunks + (long long)block * 4 - 1) / ((long long)block * 4);
        if (grid < 1) grid = 1;
        parity_apply_kernel<<<(int)grid, block, 0, stream>>>(
            (const uint4v*)h, (const uint4v*)mask, (uint4v*)out, cpr, n_chunks);
    } else {
        int grid = 2048;
        if ((long long)grid * block > n_chunks) {
            grid = (int)((n_chunks + block - 1) / block);
            if (grid < 1) grid = 1;
        }
        parity_fallback_kernel<<<grid, block, 0, stream>>>(h, S, out, dim, n_chunks);
    }
}

// Round 4
// 259.663 us; speedup vs baseline: 1.0203x; 1.0117x over previous
//
#include <hip/hip_runtime.h>
#include <math.h>

typedef unsigned int u32;
typedef __attribute__((ext_vector_type(4))) unsigned int uint4v;

// out[r][c] = h[r][c] * S[c][c], S diagonal +-1 (fp32) => XOR of fp32 sign bit.
// Kernel 1 compacts S's diagonal signs to 16 KB in d_ws.
// Kernel 2: 8 chunks (128 B) per thread, all loads issued non-temporally
// before any store (MLP=9), non-temporal stores. Distinguishes residual
// latency-boundedness from an environmental LLC/HBM drain ceiling.

__global__ __launch_bounds__(256) void parity_mask_kernel(
    const u32* __restrict__ S, u32* __restrict__ mask, int dim)
{
    const int c = blockIdx.x * blockDim.x + threadIdx.x;
    if (c < dim) mask[c] = S[(long long)c * dim + c] & 0x80000000u;
}

__global__ __launch_bounds__(256) void parity_apply_kernel(
    const uint4v* __restrict__ hv,
    const uint4v* __restrict__ maskv,   // dim/4 sign-mask chunks
    uint4v* __restrict__ ov,
    int cpr,                            // chunks per row = dim/4
    long long n_chunks)
{
    const long long tid = (long long)blockIdx.x * blockDim.x + threadIdx.x;
    const long long s   = (long long)gridDim.x * blockDim.x;

    if ((s % cpr) == 0 && tid + 7 * s < n_chunks) {
        const uint4v m = maskv[(int)(tid % cpr)];
        uint4v v[8];
#pragma unroll
        for (int k = 0; k < 8; ++k)
            v[k] = __builtin_nontemporal_load(&hv[tid + k * s]);
#pragma unroll
        for (int k = 0; k < 8; ++k) v[k] ^= m;
#pragma unroll
        for (int k = 0; k < 8; ++k)
            __builtin_nontemporal_store(v[k], &ov[tid + k * s]);
    } else {
        for (long long i = tid; i < n_chunks; i += s) {
            uint4v m = maskv[(int)(i % cpr)];
            uint4v v = __builtin_nontemporal_load(&hv[i]);
            v ^= m;
            __builtin_nontemporal_store(v, &ov[i]);
        }
    }
}

// Fallback (ws too small): read S's diagonal directly.
__global__ __launch_bounds__(256) void parity_fallback_kernel(
    const u32* __restrict__ h, const u32* __restrict__ S, u32* __restrict__ out,
    int dim, long long n_chunks)
{
    const int cpr = dim >> 2;
    const long long tid    = (long long)blockIdx.x * blockDim.x + threadIdx.x;
    const long long stride = (long long)gridDim.x * blockDim.x;
    const uint4v* hv = (const uint4v*)h;
    uint4v* ov = (uint4v*)out;
    for (long long i = tid; i < n_chunks; i += stride) {
        const int c0 = (int)(i % cpr) * 4;
        uint4v v = hv[i];
#pragma unroll
        for (int j = 0; j < 4; ++j) {
            const long long c = c0 + j;
            v[j] ^= (S[c * (long long)dim + c] & 0x80000000u);
        }
        ov[i] = v;
    }
}

extern "C" void kernel_launch(void* const* d_in, const int* in_sizes, int n_in,
                              void* d_out, int out_size, void* d_ws, size_t ws_size,
                              hipStream_t stream) {
    (void)n_in; (void)out_size;
    const u32* h = (const u32*)d_in[0];
    const u32* S = (const u32*)d_in[1];
    u32* out = (u32*)d_out;

    const long long s_elems = (long long)in_sizes[1];
    const int dim = (int)llroundl(sqrtl((long double)s_elems));  // 4096
    const long long n = (long long)in_sizes[0];
    const long long n_chunks = n >> 2;        // 4 fp32 per 16B chunk
    const int cpr = dim >> 2;                 // 1024

    const int block = 256;
    if (ws_size >= (size_t)dim * sizeof(u32) && (dim & 3) == 0) {
        u32* mask = (u32*)d_ws;
        parity_mask_kernel<<<(dim + block - 1) / block, block, 0, stream>>>(
            S, mask, dim);
        // 8 chunks/thread: grid = ceil(n_chunks / (block*8)).
        // 8192x4096: 4096 blocks; stride = 1,048,576 = 1024*1024 -> fast path.
        long long grid = (n_chunks + (long long)block * 8 - 1) / ((long long)block * 8);
        if (grid < 1) grid = 1;
        parity_apply_kernel<<<(int)grid, block, 0, stream>>>(
            (const uint4v*)h, (const uint4v*)mask, (uint4v*)out, cpr, n_chunks);
    } else {
        int grid = 2048;
        if ((long long)grid * block > n_chunks) {
            grid = (int)((n_chunks + block - 1) / block);
            if (grid < 1) grid = 1;
        }
        parity_fallback_kernel<<<grid, block, 0, stream>>>(h, S, out, dim, n_chunks);
    }
}